// Round 9
// baseline (27.702 us; speedup 1.0000x reference)
//
#include <hip/hip_runtime.h>

#define S 256
#define NF 4096
#define TILE 16
#define QTILE 4            // quarter-tile height: block = 16 wide x 4 tall
#define NT 512             // 8 slices x 64 pixels
#define SLICES 8
#define CAPC 256           // candidate slots (avg ~31 used; overflow -> exact fallback)
#define NEARF 0.1f
#define FARF 100.0f
#define EPSF 1e-8f

// 1024 blocks: block b -> tile = b & 255, quarter = b >> 8 (adjacent blocks hit
// different tiles -> decorrelated load). 4 resident blocks/CU x 8 waves = 32
// waves/CU (max occupancy); per-CU load is the sum of 4 small quarter-tiles ->
// sqrt(2) lower tail variance than R8's 2 half-tiles.
// Cull: all 4096 faces per block, 2-face register batches x4 (64-VGPR cap),
// fp32 conservative bbox+area tests vs QUARTER-tile bounds (~18% fewer
// candidates than half-tile). Edge deltas computed only for hits.
// Render: 8 slices x 64 px, precomputed deltas (bit-identical __fsub_rn
// hoisted), bit-exact __f*_rn body. Merge via (depth_bits<<32|face) min-key:
// order-independent, exact lowest-index tie-break.
__global__ __launch_bounds__(NT, 8) void raster_tile(const float* __restrict__ faces,
                                                     int* __restrict__ out) {
    __shared__ float4 s_cand[CAPC][4];          // 16 KB
    __shared__ unsigned long long s_key[NT];    // 4 KB
    __shared__ int s_cnt;

    const int bx = blockIdx.x;
    const int tile = bx & 255;
    const int quarter = bx >> 8;
    const int tx0 = (tile & (S / TILE - 1)) * TILE;
    const int ty0 = (tile / (S / TILE)) * TILE + quarter * QTILE;

    const int pix = threadIdx.x & 63;            // 16 x 4 pixels
    const int slice = threadIdx.x >> 6;          // wave index, wave-uniform
    const int px = tx0 + (pix & (TILE - 1));
    const int py = ty0 + (pix >> 4);
    // (2i+1-256)/256: odd numerator / pow2 -> exact in fp32.
    const float xp = (2.0f * px + 1.0f - 256.0f) * (1.0f / 256.0f);
    const float yp = (2.0f * py + 1.0f - 256.0f) * (1.0f / 256.0f);

    // Quarter-tile pixel-center bounds with margin vs ulp-level boundary flips.
    const float cxlo = (2.0f * tx0 + 1.0f - 256.0f) * (1.0f / 256.0f) - 1e-5f;
    const float cxhi = (2.0f * (tx0 + TILE - 1) + 1.0f - 256.0f) * (1.0f / 256.0f) + 1e-5f;
    const float cylo = (2.0f * ty0 + 1.0f - 256.0f) * (1.0f / 256.0f) - 1e-5f;
    const float cyhi = (2.0f * (ty0 + QTILE - 1) + 1.0f - 256.0f) * (1.0f / 256.0f) + 1e-5f;

    if (threadIdx.x == 0) s_cnt = 0;
    __syncthreads();

    // ---- cull: 4096 faces, 4 batches of 2 faces/thread (low VGPR) ----
#pragma unroll
    for (int g = 0; g < 4; ++g) {
        float4 A[2], B[2];
        float Cz[2];
#pragma unroll
        for (int i = 0; i < 2; ++i) {
            const int f = g * 1024 + i * NT + (int)threadIdx.x;
            const float* p = faces + (size_t)f * 9;
            A[i] = *(const float4*)p;        // x0,y0,z0,x1
            B[i] = *(const float4*)(p + 4);  // y1,z1,x2,y2
            Cz[i] = p[8];                    // z2
        }
#pragma unroll
        for (int i = 0; i < 2; ++i) {
            const float x0 = A[i].x, y0 = A[i].y, x1 = A[i].w;
            const float y1 = B[i].x, x2 = B[i].z, y2 = B[i].w;
            const float bxmin = fminf(x0, fminf(x1, x2));
            const float bxmax = fmaxf(x0, fmaxf(x1, x2));
            const float bymin = fminf(y0, fminf(y1, y2));
            const float bymax = fmaxf(y0, fmaxf(y1, y2));
            bool hit = (bxmax >= cxlo) && (bxmin <= cxhi) &&
                       (bymax >= cylo) && (bymin <= cyhi);
            if (hit) {
                // 2*signed area fp32: |err| < 1.5e-6 << 1e-4 margin -> no pixel
                // whose fp32 w_sum>0 can be lost to this cull.
                const float a2 = __fsub_rn(
                    __fmul_rn(__fsub_rn(x1, x0), __fsub_rn(y2, y0)),
                    __fmul_rn(__fsub_rn(x2, x0), __fsub_rn(y1, y0)));
                hit = (a2 > -1e-4f);
            }
            if (hit) {
                // Edge deltas: identical __fsub_rn ops to the reference's
                // per-pixel (x2-x1) etc. -> bit-identical, hoisted; computed
                // only on the ~1% hit path.
                const float dx21 = __fsub_rn(x2, x1), dy21 = __fsub_rn(y2, y1);
                const float dx02 = __fsub_rn(x0, x2), dy02 = __fsub_rn(y0, y2);
                const float dx10 = __fsub_rn(x1, x0), dy10 = __fsub_rn(y1, y0);
                const int f = g * 1024 + i * NT + (int)threadIdx.x;
                const int slot = atomicAdd(&s_cnt, 1);
                if (slot < CAPC) {
                    s_cand[slot][0] = A[i];
                    s_cand[slot][1] = B[i];
                    s_cand[slot][2] =
                        make_float4(Cz[i], __int_as_float(f), dx21, dy21);
                    s_cand[slot][3] = make_float4(dx02, dy02, dx10, dy10);
                }
            }
        }
    }
    __syncthreads();

    float bestd = FARF;
    int bestf = 0x7fffffff;

    const int n = s_cnt;
    if (n <= CAPC) {
        // ---- render: 8-sliced scan, deltas precomputed ----
        for (int i = slice; i < n; i += SLICES) {
            const float4 a = s_cand[i][0];   // broadcast reads, conflict-free
            const float4 b = s_cand[i][1];
            const float4 c = s_cand[i][2];
            const float4 d = s_cand[i][3];
            const float X0 = a.x, Y0 = a.y, Z0 = a.z, X1 = a.w;
            const float Y1 = b.x, Z1 = b.y, X2 = b.z, Y2 = b.w;
            const float Z2 = c.x;
            const int f = __float_as_int(c.y);
            const float w0 = __fsub_rn(__fmul_rn(__fsub_rn(yp, Y1), c.z),
                                       __fmul_rn(__fsub_rn(xp, X1), c.w));
            const float w1 = __fsub_rn(__fmul_rn(__fsub_rn(yp, Y2), d.x),
                                       __fmul_rn(__fsub_rn(xp, X2), d.y));
            const float w2 = __fsub_rn(__fmul_rn(__fsub_rn(yp, Y0), d.z),
                                       __fmul_rn(__fsub_rn(xp, X0), d.w));
            const bool inside = (__fmul_rn(w0, w1) > 0.0f) && (__fmul_rn(w1, w2) > 0.0f);
            const float wsum = __fadd_rn(__fadd_rn(w0, w1), w2);
            if (inside && (wsum > 0.0f)) {
                float denom = __fadd_rn(__fadd_rn(__fdiv_rn(w0, Z0), __fdiv_rn(w1, Z1)),
                                        __fdiv_rn(w2, Z2));
                denom = (fabsf(denom) > EPSF) ? denom : EPSF;
                const float zp = __fdiv_rn(wsum, denom);
                if ((zp > NEARF) && (zp < FARF)) {
                    if (zp < bestd || (zp == bestd && f < bestf)) {
                        bestd = zp;
                        bestf = f;
                    }
                }
            }
        }
    } else {
        // Overflow (never expected): test every face directly from global.
        // Conservative-cull equivalence keeps this exact.
        for (int i = slice; i < NF; i += SLICES) {
            const float* p = faces + (size_t)i * 9;
            const float X0 = p[0], Y0 = p[1], Z0 = p[2];
            const float X1 = p[3], Y1 = p[4], Z1 = p[5];
            const float X2 = p[6], Y2 = p[7], Z2 = p[8];
            const float w0 = __fsub_rn(__fmul_rn(__fsub_rn(yp, Y1), __fsub_rn(X2, X1)),
                                       __fmul_rn(__fsub_rn(xp, X1), __fsub_rn(Y2, Y1)));
            const float w1 = __fsub_rn(__fmul_rn(__fsub_rn(yp, Y2), __fsub_rn(X0, X2)),
                                       __fmul_rn(__fsub_rn(xp, X2), __fsub_rn(Y0, Y2)));
            const float w2 = __fsub_rn(__fmul_rn(__fsub_rn(yp, Y0), __fsub_rn(X1, X0)),
                                       __fmul_rn(__fsub_rn(xp, X0), __fsub_rn(Y1, Y0)));
            const bool inside = (__fmul_rn(w0, w1) > 0.0f) && (__fmul_rn(w1, w2) > 0.0f);
            const float wsum = __fadd_rn(__fadd_rn(w0, w1), w2);
            if (inside && (wsum > 0.0f)) {
                float denom = __fadd_rn(__fadd_rn(__fdiv_rn(w0, Z0), __fdiv_rn(w1, Z1)),
                                        __fdiv_rn(w2, Z2));
                denom = (fabsf(denom) > EPSF) ? denom : EPSF;
                const float zp = __fdiv_rn(wsum, denom);
                if ((zp > NEARF) && (zp < FARF)) {
                    if (zp < bestd || (zp == bestd && i < bestf)) {
                        bestd = zp;
                        bestf = i;
                    }
                }
            }
        }
    }

    // ---- merge 8 slices per pixel via packed min-key ----
    s_key[threadIdx.x] =
        ((unsigned long long)__float_as_uint(bestd) << 32) | (unsigned int)bestf;
    __syncthreads();
    if (threadIdx.x < 64) {
        unsigned long long k = s_key[threadIdx.x];
#pragma unroll
        for (int s = 1; s < SLICES; ++s) {
            const unsigned long long ks = s_key[threadIdx.x + 64 * s];
            k = ks < k ? ks : k;
        }
        const float dd = __uint_as_float((unsigned int)(k >> 32));
        const int fi = (int)(unsigned int)k;
        const int opx = tx0 + (threadIdx.x & (TILE - 1));
        const int opy = ty0 + (threadIdx.x >> 4);
        out[opy * S + opx] = (dd < FARF) ? fi : -1;
    }
}

extern "C" void kernel_launch(void* const* d_in, const int* in_sizes, int n_in,
                              void* d_out, int out_size, void* d_ws, size_t ws_size,
                              hipStream_t stream) {
    const float* faces = (const float*)d_in[0];
    int* out = (int*)d_out;
    hipLaunchKernelGGL(raster_tile, dim3(4 * (S / TILE) * (S / TILE)), dim3(NT), 0,
                       stream, faces, out);
}